// Round 4
// baseline (555.194 us; speedup 1.0000x reference)
//
#include <hip/hip_runtime.h>

#define HDIM 256
constexpr int N_SRC = 131072, N_MID = 32768, N_DST = 8192;
constexpr int E1 = 524288, E2 = 131072;
constexpr int N_PAIRS = 8192;

typedef __attribute__((ext_vector_type(8))) short bf16x8;
typedef __attribute__((ext_vector_type(4))) float f32x4;

__device__ __forceinline__ float bf2f(unsigned short u) {
    return __uint_as_float(((unsigned int)u) << 16);
}
__device__ __forceinline__ unsigned short f2bf(float f) {
    unsigned int x = __float_as_uint(f);
    x += 0x7fff + ((x >> 16) & 1);          // round-to-nearest-even
    return (unsigned short)(x >> 16);
}

// ---------------------------------------------------------------------------
// W-resident streaming GEMM:  C[M,256] = act( [A0|A1] @ W^T + bias ), bf16 out.
// The full weight chunk (NCOLS x KTOT) lives in LDS for the whole kernel
// (staged once, fp32->bf16, one barrier). Each wave then free-runs over
// 32-row chunks of A with NO further barriers: all A fragments are issued
// as independent global loads up front (deep MLP), B frags come from LDS.
// NCOLS=256: whole output row per block. NCOLS=128: blockIdx.y = col half.
// LDS k-stride padded +8 shorts -> (KTOT+8)*2 B = 4 mod 32 words: 2-way (free).
// ---------------------------------------------------------------------------
template<int KTOT, int NCOLS, int FP32A, int ACT>
__global__ __launch_bounds__(512, 2)
void stream_gemm(const void* __restrict__ A0v, const void* __restrict__ A1v,
                 const float* __restrict__ Wf, const float* __restrict__ bias,
                 unsigned short* __restrict__ C, int M)
{
    constexpr int KS = KTOT / 32;       // k-slices per row
    constexpr int NF = NCOLS / 16;      // col fragments
    __shared__ unsigned short Ws[NCOLS][KTOT + 8];

    const int t = threadIdx.x;
    const int coff = blockIdx.y * NCOLS;
    const float* W = Wf + (size_t)coff * KTOT;

    // ---- stage W into LDS (fp32 -> bf16), 128 elems per thread ----
    {
        constexpr int TPC = 512 / NCOLS;           // threads per col (2 or 4)
        constexpr int CHUNK = KTOT / TPC;          // 128
        const int col = t / TPC;
        const int kb  = (t % TPC) * CHUNK;
        for (int j = 0; j < CHUNK; j += 4) {
            const float4 v = *reinterpret_cast<const float4*>(&W[(size_t)col * KTOT + kb + j]);
            ushort4 o;
            o.x = f2bf(v.x); o.y = f2bf(v.y); o.z = f2bf(v.z); o.w = f2bf(v.w);
            *reinterpret_cast<ushort4*>(&Ws[col][kb + j]) = o;
        }
    }
    __syncthreads();

    const int lane = t & 63;
    const int l15  = lane & 15;
    const int lk   = (lane >> 4) * 8;
    const int rb   = (lane >> 4) * 4;

    float bfv[NF];
#pragma unroll
    for (int n = 0; n < NF; ++n) bfv[n] = bias[coff + n * 16 + l15];

    const int gw = blockIdx.x * 8 + (t >> 6);
    const int GW = gridDim.x * 8;

    for (int r0 = gw * 32; r0 < M; r0 += GW * 32) {
        // ---- issue all A fragment loads (independent, stay in flight) ----
        bf16x8 af[2][KS];
#pragma unroll
        for (int rg = 0; rg < 2; ++rg) {
            const int row = r0 + rg * 16 + l15;
#pragma unroll
            for (int ks = 0; ks < KS; ++ks) {
                const int k = ks * 32 + lk;
                if constexpr (FP32A) {
                    const float* ap = (const float*)A0v + (size_t)row * 256 + k;
                    const float4 u0 = *reinterpret_cast<const float4*>(ap);
                    const float4 u1 = *reinterpret_cast<const float4*>(ap + 4);
                    bf16x8 r;
                    r[0] = (short)f2bf(u0.x); r[1] = (short)f2bf(u0.y);
                    r[2] = (short)f2bf(u0.z); r[3] = (short)f2bf(u0.w);
                    r[4] = (short)f2bf(u1.x); r[5] = (short)f2bf(u1.y);
                    r[6] = (short)f2bf(u1.z); r[7] = (short)f2bf(u1.w);
                    af[rg][ks] = r;
                } else {
                    const unsigned short* ap = (k < 256)
                        ? (const unsigned short*)A0v + (size_t)row * 256 + k
                        : (const unsigned short*)A1v + (size_t)row * 256 + (k - 256);
                    af[rg][ks] = *reinterpret_cast<const bf16x8*>(ap);
                }
            }
        }
        // ---- MFMA: B frag shared across both row groups ----
        f32x4 acc[2][NF];
#pragma unroll
        for (int rg = 0; rg < 2; ++rg)
#pragma unroll
            for (int n = 0; n < NF; ++n) acc[rg][n] = (f32x4){0.f, 0.f, 0.f, 0.f};
#pragma unroll
        for (int ks = 0; ks < KS; ++ks) {
#pragma unroll
            for (int n = 0; n < NF; ++n) {
                const bf16x8 b = *reinterpret_cast<const bf16x8*>(&Ws[n * 16 + l15][ks * 32 + lk]);
                acc[0][n] = __builtin_amdgcn_mfma_f32_16x16x32_bf16(af[0][ks], b, acc[0][n], 0, 0, 0);
                acc[1][n] = __builtin_amdgcn_mfma_f32_16x16x32_bf16(af[1][ks], b, acc[1][n], 0, 0, 0);
            }
        }
        // ---- epilogue ----
#pragma unroll
        for (int rg = 0; rg < 2; ++rg) {
            const int row0 = r0 + rg * 16 + rb;
#pragma unroll
            for (int n = 0; n < NF; ++n) {
                const int col = coff + n * 16 + l15;
#pragma unroll
                for (int j = 0; j < 4; ++j) {
                    float v = acc[rg][n][j] + bfv[n];
                    if (ACT) v = fmaxf(v, 0.f);
                    C[(size_t)(row0 + j) * 256 + col] = f2bf(v);
                }
            }
        }
    }
}

// ---------------------------------------------------------------------------
// CSR build: count -> scan -> fill (fill scatters src & w into CSR order)
// ---------------------------------------------------------------------------
__global__ void edge_count(const int* __restrict__ dst, int E, int* __restrict__ counts)
{
    int i = blockIdx.x * blockDim.x + threadIdx.x;
    const int stride = gridDim.x * blockDim.x;
    for (; i < E; i += stride) atomicAdd(&counts[dst[i]], 1);
}

__global__ __launch_bounds__(1024)
void scan_kernel(const int* __restrict__ counts, int n,
                 int* __restrict__ row_start, int* __restrict__ cursor)
{
    __shared__ int part[1024];
    const int t = threadIdx.x;
    const int per = n >> 10;
    const int base = t * per;
    int s = 0;
    for (int j = 0; j < per; ++j) s += counts[base + j];
    part[t] = s;
    __syncthreads();
    for (int off = 1; off < 1024; off <<= 1) {
        int v = (t >= off) ? part[t - off] : 0;
        __syncthreads();
        part[t] += v;
        __syncthreads();
    }
    int run = (t == 0) ? 0 : part[t - 1];
    for (int j = 0; j < per; ++j) {
        row_start[base + j] = run;
        cursor[base + j] = run;
        run += counts[base + j];
    }
    if (t == 1023) row_start[n] = run;
}

__global__ void edge_fill(const int* __restrict__ dst, const int* __restrict__ src,
                          const float* __restrict__ w, int E,
                          int* __restrict__ cursor,
                          int* __restrict__ ssrc, float* __restrict__ sw)
{
    int i = blockIdx.x * blockDim.x + threadIdx.x;
    const int stride = gridDim.x * blockDim.x;
    for (; i < E; i += stride) {
        const int p = atomicAdd(&cursor[dst[i]], 1);
        ssrc[p] = src[i];
        sw[p]   = w[i];
    }
}

// ---------------------------------------------------------------------------
// Weighted aggregate with 4x memory-level parallelism (one wave per dst row).
// ---------------------------------------------------------------------------
__global__ __launch_bounds__(256)
void aggregate(const unsigned short* __restrict__ nsrc,
               const int* __restrict__ ssrc, const float* __restrict__ sw,
               const int* __restrict__ rs, unsigned short* __restrict__ agg)
{
    const int d = blockIdx.x * 4 + (threadIdx.x >> 6);
    const int lane = threadIdx.x & 63;
    const int p0 = rs[d], p1 = rs[d + 1];
    float a0 = 0.f, a1 = 0.f, a2 = 0.f, a3 = 0.f, wacc = 0.f;

    for (int base = p0; base < p1; base += 64) {
        const int cnt = min(64, p1 - base);
        int   mySrc = 0;
        float myW   = 0.f;
        if (lane < cnt) { mySrc = ssrc[base + lane]; myW = sw[base + lane]; }
        wacc += myW;
        int j = 0;
        for (; j + 4 <= cnt; j += 4) {
            const int   s0 = __shfl(mySrc, j + 0), s1 = __shfl(mySrc, j + 1);
            const int   s2 = __shfl(mySrc, j + 2), s3 = __shfl(mySrc, j + 3);
            const float w0 = __shfl(myW, j + 0),   w1 = __shfl(myW, j + 1);
            const float w2 = __shfl(myW, j + 2),   w3 = __shfl(myW, j + 3);
            const ushort4 r0 = *reinterpret_cast<const ushort4*>(&nsrc[(size_t)s0 * 256 + lane * 4]);
            const ushort4 r1 = *reinterpret_cast<const ushort4*>(&nsrc[(size_t)s1 * 256 + lane * 4]);
            const ushort4 r2 = *reinterpret_cast<const ushort4*>(&nsrc[(size_t)s2 * 256 + lane * 4]);
            const ushort4 r3 = *reinterpret_cast<const ushort4*>(&nsrc[(size_t)s3 * 256 + lane * 4]);
            a0 += bf2f(r0.x) * w0; a1 += bf2f(r0.y) * w0; a2 += bf2f(r0.z) * w0; a3 += bf2f(r0.w) * w0;
            a0 += bf2f(r1.x) * w1; a1 += bf2f(r1.y) * w1; a2 += bf2f(r1.z) * w1; a3 += bf2f(r1.w) * w1;
            a0 += bf2f(r2.x) * w2; a1 += bf2f(r2.y) * w2; a2 += bf2f(r2.z) * w2; a3 += bf2f(r2.w) * w2;
            a0 += bf2f(r3.x) * w3; a1 += bf2f(r3.y) * w3; a2 += bf2f(r3.z) * w3; a3 += bf2f(r3.w) * w3;
        }
        for (; j < cnt; ++j) {
            const int   s = __shfl(mySrc, j);
            const float wj = __shfl(myW, j);
            const ushort4 r = *reinterpret_cast<const ushort4*>(&nsrc[(size_t)s * 256 + lane * 4]);
            a0 += bf2f(r.x) * wj; a1 += bf2f(r.y) * wj; a2 += bf2f(r.z) * wj; a3 += bf2f(r.w) * wj;
        }
    }
    float ws = wacc;
#pragma unroll
    for (int off = 32; off > 0; off >>= 1) ws += __shfl_xor(ws, off);
    const float inv = 1.f / fmaxf(ws, 1.f);
    ushort4 o;
    o.x = f2bf(a0 * inv); o.y = f2bf(a1 * inv);
    o.z = f2bf(a2 * inv); o.w = f2bf(a3 * inv);
    *reinterpret_cast<ushort4*>(&agg[(size_t)d * 256 + lane * 4]) = o;
}

// ---------------------------------------------------------------------------
// z = normalize(hp[:N_DST] + h2)   (bf16 in, fp32 out)
// ---------------------------------------------------------------------------
__global__ __launch_bounds__(256)
void skip_norm(const unsigned short* __restrict__ hp, const unsigned short* __restrict__ h2,
               float* __restrict__ z)
{
    __shared__ float sm[4];
    const int d = blockIdx.x, t = threadIdx.x;
    const float v = bf2f(hp[(size_t)d * 256 + t]) + bf2f(h2[(size_t)d * 256 + t]);
    float s = v * v;
#pragma unroll
    for (int off = 32; off > 0; off >>= 1) s += __shfl_down(s, off);
    if ((t & 63) == 0) sm[t >> 6] = s;
    __syncthreads();
    const float tot = sm[0] + sm[1] + sm[2] + sm[3];
    const float nrm = sqrtf(tot);
    const float inv = (nrm == 0.f) ? 1.f : 1.f / nrm;
    z[(size_t)d * 256 + t] = v * inv;
}

// ---------------------------------------------------------------------------
__global__ __launch_bounds__(256)
void score_kernel(const float* __restrict__ z, const float* __restrict__ bias,
                  const int* __restrict__ nids,
                  const int* __restrict__ ps, const int* __restrict__ pd,
                  const int* __restrict__ ns, const int* __restrict__ nd,
                  float* __restrict__ out)
{
    __shared__ float sm[8];
    const int p = blockIdx.x, t = threadIdx.x;
    const int a = ps[p], b = pd[p], c = ns[p], d2 = nd[p];
    float vp = z[(size_t)a * 256 + t] * z[(size_t)b * 256 + t];
    float vn = z[(size_t)c * 256 + t] * z[(size_t)d2 * 256 + t];
#pragma unroll
    for (int off = 32; off > 0; off >>= 1) {
        vp += __shfl_down(vp, off);
        vn += __shfl_down(vn, off);
    }
    if ((t & 63) == 0) { sm[t >> 6] = vp; sm[4 + (t >> 6)] = vn; }
    __syncthreads();
    if (t == 0) {
        const float pos = sm[0] + sm[1] + sm[2] + sm[3] + bias[nids[a]] + bias[nids[b]];
        const float neg = sm[4] + sm[5] + sm[6] + sm[7] + bias[nids[c]] + bias[nids[d2]];
        out[p] = fmaxf(neg - pos + 1.0f, 0.f);
    }
}

// ---------------------------------------------------------------------------
extern "C" void kernel_launch(void* const* d_in, const int* in_sizes, int n_in,
                              void* d_out, int out_size, void* d_ws, size_t ws_size,
                              hipStream_t stream)
{
    const float* feat = (const float*)d_in[0];
    const float* Wp   = (const float*)d_in[1];
    const float* bp   = (const float*)d_in[2];
    const float* Q1   = (const float*)d_in[3];
    const float* bq1  = (const float*)d_in[4];
    const float* W1   = (const float*)d_in[5];
    const float* bw1  = (const float*)d_in[6];
    const float* Q2   = (const float*)d_in[7];
    const float* bq2  = (const float*)d_in[8];
    const float* W2   = (const float*)d_in[9];
    const float* bw2  = (const float*)d_in[10];
    const float* w1   = (const float*)d_in[11];
    const float* w2   = (const float*)d_in[12];
    const float* bias = (const float*)d_in[13];
    const int* src1   = (const int*)d_in[14];
    const int* dst1   = (const int*)d_in[15];
    const int* src2   = (const int*)d_in[16];
    const int* dst2   = (const int*)d_in[17];
    const int* pos_src = (const int*)d_in[18];
    const int* pos_dst = (const int*)d_in[19];
    const int* neg_src = (const int*)d_in[20];
    const int* neg_dst = (const int*)d_in[21];
    const int* nids    = (const int*)d_in[22];

    // workspace layout (bf16 intermediates + CSR with scattered src/w)
    unsigned short* hp   = (unsigned short*)d_ws;              // [N_SRC,256]
    unsigned short* n1   = hp   + (size_t)N_SRC * 256;         // [N_SRC,256] (reused as n2)
    unsigned short* aggb = n1   + (size_t)N_SRC * 256;         // [N_MID,256] (reused as agg2)
    unsigned short* h1   = aggb + (size_t)N_MID * 256;         // [N_MID,256]
    unsigned short* h2   = h1   + (size_t)N_MID * 256;         // [N_DST,256]
    float* zb            = (float*)(h2 + (size_t)N_DST * 256); // [N_DST,256] fp32
    int* counts1 = (int*)(zb + (size_t)N_DST * 256);
    int* rs1     = counts1 + N_MID;
    int* cur1    = rs1 + N_MID + 1;
    int* ssrc1   = cur1 + N_MID;
    float* sw1   = (float*)(ssrc1 + E1);
    int* counts2 = (int*)(sw1 + E1);
    int* rs2     = counts2 + N_DST;
    int* cur2    = rs2 + N_DST + 1;
    int* ssrc2   = cur2 + N_DST;
    float* sw2   = (float*)(ssrc2 + E2);

    hipMemsetAsync(counts1, 0, N_MID * sizeof(int), stream);
    hipMemsetAsync(counts2, 0, N_DST * sizeof(int), stream);

    const dim3 blk(256);

    // hp = feat @ Wp^T + bp   (fp32 A, converted inline)
    stream_gemm<256, 256, 1, 0><<<dim3(256, 1), 512, 0, stream>>>(
        feat, nullptr, Wp, bp, hp, N_SRC);
    // n1 = relu(hp @ Q1^T + bq1)
    stream_gemm<256, 256, 0, 1><<<dim3(256, 1), 512, 0, stream>>>(
        hp, nullptr, Q1, bq1, n1, N_SRC);

    // conv1 aggregation
    edge_count<<<1024, blk, 0, stream>>>(dst1, E1, counts1);
    scan_kernel<<<1, 1024, 0, stream>>>(counts1, N_MID, rs1, cur1);
    edge_fill<<<1024, blk, 0, stream>>>(dst1, src1, w1, E1, cur1, ssrc1, sw1);
    aggregate<<<N_MID / 4, blk, 0, stream>>>(n1, ssrc1, sw1, rs1, aggb);

    // h1 = relu( [agg1 | hp[:N_MID]] @ W1^T + bw1 )   (K=512, col-halves)
    stream_gemm<512, 128, 0, 1><<<dim3(128, 2), 512, 0, stream>>>(
        aggb, hp, W1, bw1, h1, N_MID);

    // n2 = relu(h1 @ Q2^T + bq2)   (into n1 buffer)
    stream_gemm<256, 256, 0, 1><<<dim3(128, 1), 512, 0, stream>>>(
        h1, nullptr, Q2, bq2, n1, N_MID);

    // conv2 aggregation
    edge_count<<<512, blk, 0, stream>>>(dst2, E2, counts2);
    scan_kernel<<<1, 1024, 0, stream>>>(counts2, N_DST, rs2, cur2);
    edge_fill<<<512, blk, 0, stream>>>(dst2, src2, w2, E2, cur2, ssrc2, sw2);
    aggregate<<<N_DST / 4, blk, 0, stream>>>(n1, ssrc2, sw2, rs2, aggb);

    // h2 = relu( [agg2 | h1[:N_DST]] @ W2^T + bw2 )   (K=512, col-halves)
    stream_gemm<512, 128, 0, 1><<<dim3(32, 2), 512, 0, stream>>>(
        aggb, h1, W2, bw2, h2, N_DST);

    // z = normalize(hp[:N_DST] + h2); scores
    skip_norm<<<N_DST, blk, 0, stream>>>(hp, h2, zb);
    score_kernel<<<N_PAIRS, blk, 0, stream>>>(zb, bias, nids,
                                              pos_src, pos_dst, neg_src, neg_dst,
                                              (float*)d_out);
}

// Round 5
// 368.218 us; speedup vs baseline: 1.5078x; 1.5078x over previous
//
#include <hip/hip_runtime.h>

#define HDIM 256
constexpr int N_SRC = 131072, N_MID = 32768, N_DST = 8192;
constexpr int E1 = 524288, E2 = 131072;
constexpr int N_PAIRS = 8192;

typedef __attribute__((ext_vector_type(8))) short bf16x8;
typedef __attribute__((ext_vector_type(4))) float f32x4;

__device__ __forceinline__ float bf2f(unsigned short u) {
    return __uint_as_float(((unsigned int)u) << 16);
}
__device__ __forceinline__ unsigned short f2bf(float f) {
    unsigned int x = __float_as_uint(f);
    x += 0x7fff + ((x >> 16) & 1);          // round-to-nearest-even
    return (unsigned short)(x >> 16);
}

// async global->LDS, 16B per lane; LDS dest = wave-uniform base + lane*16
__device__ __forceinline__ void gl16(const void* g, void* l)
{
    __builtin_amdgcn_global_load_lds(
        (const __attribute__((address_space(1))) unsigned int*)g,
        (__attribute__((address_space(3))) unsigned int*)l, 16, 0, 0);
}

// ---------------------------------------------------------------------------
// GEMM: C[M,256] = act( [A0|A1] @ W^T + bias ), bf16 out.
// Tile 64 rows x 256 cols per block (A read exactly once), BK=64,
// 512 threads = 8 waves, wave = 32x64 (wrow=w>>2, wc=w&3), acc 2x4 f32x4.
// Staging via global_load_lds(16B): LDS linear, 16B chunk index XOR-swizzled
// (kc ^= row&7) on the GLOBAL source; ds_read applies the same swizzle ->
// conflict-free frag reads (G21 both-sides pattern).
// W: bf16 [256][KTOT] preconverted (L2-resident). A: bf16, or fp32 (FP32A,
// staged as fp32 and converted at frag-read).
// ---------------------------------------------------------------------------
template<int KTOT, int FP32A, int ACT>
__global__ __launch_bounds__(512, 4)
void gemm_k(const void* __restrict__ A0v, const void* __restrict__ A1v,
            const unsigned short* __restrict__ Wb,
            const float* __restrict__ bias,
            unsigned short* __restrict__ C, int M)
{
    constexpr int KSTEPS = KTOT / 64;
    __shared__ unsigned short sW[256 * 64];                  // 32 KB
    __shared__ unsigned char  sA[FP32A ? 16384 : 8192];      // fp32: 16 KB
    unsigned char* sWb = (unsigned char*)sW;

    const int t = threadIdx.x;
    const int w = t >> 6, lane = t & 63;
    const int l15 = lane & 15;
    const int wrow = w >> 2, wc = w & 3;
    const int bm = blockIdx.x * 64;

    f32x4 acc[2][4];
#pragma unroll
    for (int m = 0; m < 2; ++m)
#pragma unroll
        for (int n = 0; n < 4; ++n) acc[m][n] = (f32x4){0.f, 0.f, 0.f, 0.f};

    for (int ks = 0; ks < KSTEPS; ++ks) {
        const int kw = ks * 64;
        // ---- stage W slice 256x64 (2048 slots, 4 iters) ----
#pragma unroll
        for (int it = 0; it < 4; ++it) {
            const int slot = it * 512 + w * 64 + lane;
            const int row = slot >> 3, kc = slot & 7;
            const int kcs = kc ^ (row & 7);
            gl16(&Wb[(size_t)row * KTOT + kw + kcs * 8],
                 sWb + (it * 512 + w * 64) * 16);
        }
        // ---- stage A slice 64x64 ----
        if constexpr (FP32A) {
            const float* A = (const float*)A0v;
#pragma unroll
            for (int it = 0; it < 2; ++it) {
                const int slot = it * 512 + w * 64 + lane;
                const int row = slot >> 4, kc = slot & 15;
                const int kcs = kc ^ (row & 7);
                gl16(&A[(size_t)(bm + row) * 256 + kw + kcs * 4],
                     sA + (it * 512 + w * 64) * 16);
            }
        } else {
            const unsigned short* A = (const unsigned short*)
                ((KTOT == 512 && ks >= 4) ? A1v : A0v);
            const int ka = (KTOT == 512) ? (ks & 3) * 64 : kw;
            const int slot = w * 64 + lane;
            const int row = slot >> 3, kc = slot & 7;
            const int kcs = kc ^ (row & 7);
            gl16(&A[(size_t)(bm + row) * 256 + ka + kcs * 8],
                 sA + (w * 64) * 16);
        }
        __syncthreads();   // drains vmcnt(0) then barrier

        // ---- compute: 2 k-slices x (2m x 4n) MFMA ----
#pragma unroll
        for (int kk = 0; kk < 2; ++kk) {
            const int kc = kk * 4 + (lane >> 4);
            bf16x8 afr[2], bfr[4];
#pragma unroll
            for (int m = 0; m < 2; ++m) {
                const int row = wrow * 32 + m * 16 + l15;
                if constexpr (FP32A) {
                    const int c0 = kk * 8 + (lane >> 4) * 2;
                    const float4 u0 = *(const float4*)(sA +
                        (((row << 4) | (c0 ^ (row & 7))) * 16));
                    const float4 u1 = *(const float4*)(sA +
                        (((row << 4) | ((c0 + 1) ^ (row & 7))) * 16));
                    bf16x8 r;
                    r[0] = (short)f2bf(u0.x); r[1] = (short)f2bf(u0.y);
                    r[2] = (short)f2bf(u0.z); r[3] = (short)f2bf(u0.w);
                    r[4] = (short)f2bf(u1.x); r[5] = (short)f2bf(u1.y);
                    r[6] = (short)f2bf(u1.z); r[7] = (short)f2bf(u1.w);
                    afr[m] = r;
                } else {
                    afr[m] = *(const bf16x8*)(sA +
                        (((row << 3) | (kc ^ (row & 7))) * 16));
                }
            }
#pragma unroll
            for (int n = 0; n < 4; ++n) {
                const int r = wc * 64 + n * 16 + l15;
                bfr[n] = *(const bf16x8*)(sWb +
                    (((r << 3) | (kc ^ (r & 7))) * 16));
            }
#pragma unroll
            for (int m = 0; m < 2; ++m)
#pragma unroll
                for (int n = 0; n < 4; ++n)
                    acc[m][n] = __builtin_amdgcn_mfma_f32_16x16x32_bf16(
                        afr[m], bfr[n], acc[m][n], 0, 0, 0);
        }
        __syncthreads();
    }

    // ---- epilogue: bias + act + bf16 store (burst; block covers full rows) --
    const int rb = (lane >> 4) * 4;
#pragma unroll
    for (int n = 0; n < 4; ++n) {
        const int col = wc * 64 + n * 16 + l15;
        const float bv = bias[col];
#pragma unroll
        for (int m = 0; m < 2; ++m) {
            const int row0 = bm + wrow * 32 + m * 16 + rb;
#pragma unroll
            for (int j = 0; j < 4; ++j) {
                float v = acc[m][n][j] + bv;
                if (ACT) v = fmaxf(v, 0.f);
                C[(size_t)(row0 + j) * 256 + col] = f2bf(v);
            }
        }
    }
}

// ---------------------------------------------------------------------------
// Convert the 5 weight matrices fp32 -> bf16
// layout: [Wp 65536][Q1 65536][W1 131072][Q2 65536][W2 131072]
// ---------------------------------------------------------------------------
__global__ __launch_bounds__(256)
void conv_w(const float* __restrict__ Wp, const float* __restrict__ Q1,
            const float* __restrict__ W1, const float* __restrict__ Q2,
            const float* __restrict__ W2, unsigned short* __restrict__ out)
{
    const int i = blockIdx.x * 256 + threadIdx.x;
    const float* src; int off;
    if (i < 65536)       { src = Wp; off = i; }
    else if (i < 131072) { src = Q1; off = i - 65536; }
    else if (i < 262144) { src = W1; off = i - 131072; }
    else if (i < 327680) { src = Q2; off = i - 262144; }
    else                 { src = W2; off = i - 327680; }
    out[i] = f2bf(src[off]);
}

// ---------------------------------------------------------------------------
// CSR build: count -> scan -> fill (fill scatters src & w into CSR order)
// ---------------------------------------------------------------------------
__global__ void edge_count(const int* __restrict__ dst, int E, int* __restrict__ counts)
{
    int i = blockIdx.x * blockDim.x + threadIdx.x;
    const int stride = gridDim.x * blockDim.x;
    for (; i < E; i += stride) atomicAdd(&counts[dst[i]], 1);
}

__global__ __launch_bounds__(1024)
void scan_kernel(const int* __restrict__ counts, int n,
                 int* __restrict__ row_start, int* __restrict__ cursor)
{
    __shared__ int part[1024];
    const int t = threadIdx.x;
    const int per = n >> 10;
    const int base = t * per;
    int s = 0;
    for (int j = 0; j < per; ++j) s += counts[base + j];
    part[t] = s;
    __syncthreads();
    for (int off = 1; off < 1024; off <<= 1) {
        int v = (t >= off) ? part[t - off] : 0;
        __syncthreads();
        part[t] += v;
        __syncthreads();
    }
    int run = (t == 0) ? 0 : part[t - 1];
    for (int j = 0; j < per; ++j) {
        row_start[base + j] = run;
        cursor[base + j] = run;
        run += counts[base + j];
    }
    if (t == 1023) row_start[n] = run;
}

__global__ void edge_fill(const int* __restrict__ dst, const int* __restrict__ src,
                          const float* __restrict__ w, int E,
                          int* __restrict__ cursor,
                          int* __restrict__ ssrc, float* __restrict__ sw)
{
    int i = blockIdx.x * blockDim.x + threadIdx.x;
    const int stride = gridDim.x * blockDim.x;
    for (; i < E; i += stride) {
        const int p = atomicAdd(&cursor[dst[i]], 1);
        ssrc[p] = src[i];
        sw[p]   = w[i];
    }
}

// ---------------------------------------------------------------------------
// Weighted aggregate with 4x memory-level parallelism (one wave per dst row).
// ---------------------------------------------------------------------------
__global__ __launch_bounds__(256)
void aggregate(const unsigned short* __restrict__ nsrc,
               const int* __restrict__ ssrc, const float* __restrict__ sw,
               const int* __restrict__ rs, unsigned short* __restrict__ agg)
{
    const int d = blockIdx.x * 4 + (threadIdx.x >> 6);
    const int lane = threadIdx.x & 63;
    const int p0 = rs[d], p1 = rs[d + 1];
    float a0 = 0.f, a1 = 0.f, a2 = 0.f, a3 = 0.f, wacc = 0.f;

    for (int base = p0; base < p1; base += 64) {
        const int cnt = min(64, p1 - base);
        int   mySrc = 0;
        float myW   = 0.f;
        if (lane < cnt) { mySrc = ssrc[base + lane]; myW = sw[base + lane]; }
        wacc += myW;
        int j = 0;
        for (; j + 4 <= cnt; j += 4) {
            const int   s0 = __shfl(mySrc, j + 0), s1 = __shfl(mySrc, j + 1);
            const int   s2 = __shfl(mySrc, j + 2), s3 = __shfl(mySrc, j + 3);
            const float w0 = __shfl(myW, j + 0),   w1 = __shfl(myW, j + 1);
            const float w2 = __shfl(myW, j + 2),   w3 = __shfl(myW, j + 3);
            const ushort4 r0 = *reinterpret_cast<const ushort4*>(&nsrc[(size_t)s0 * 256 + lane * 4]);
            const ushort4 r1 = *reinterpret_cast<const ushort4*>(&nsrc[(size_t)s1 * 256 + lane * 4]);
            const ushort4 r2 = *reinterpret_cast<const ushort4*>(&nsrc[(size_t)s2 * 256 + lane * 4]);
            const ushort4 r3 = *reinterpret_cast<const ushort4*>(&nsrc[(size_t)s3 * 256 + lane * 4]);
            a0 += bf2f(r0.x) * w0; a1 += bf2f(r0.y) * w0; a2 += bf2f(r0.z) * w0; a3 += bf2f(r0.w) * w0;
            a0 += bf2f(r1.x) * w1; a1 += bf2f(r1.y) * w1; a2 += bf2f(r1.z) * w1; a3 += bf2f(r1.w) * w1;
            a0 += bf2f(r2.x) * w2; a1 += bf2f(r2.y) * w2; a2 += bf2f(r2.z) * w2; a3 += bf2f(r2.w) * w2;
            a0 += bf2f(r3.x) * w3; a1 += bf2f(r3.y) * w3; a2 += bf2f(r3.z) * w3; a3 += bf2f(r3.w) * w3;
        }
        for (; j < cnt; ++j) {
            const int   s = __shfl(mySrc, j);
            const float wj = __shfl(myW, j);
            const ushort4 r = *reinterpret_cast<const ushort4*>(&nsrc[(size_t)s * 256 + lane * 4]);
            a0 += bf2f(r.x) * wj; a1 += bf2f(r.y) * wj; a2 += bf2f(r.z) * wj; a3 += bf2f(r.w) * wj;
        }
    }
    float ws = wacc;
#pragma unroll
    for (int off = 32; off > 0; off >>= 1) ws += __shfl_xor(ws, off);
    const float inv = 1.f / fmaxf(ws, 1.f);
    ushort4 o;
    o.x = f2bf(a0 * inv); o.y = f2bf(a1 * inv);
    o.z = f2bf(a2 * inv); o.w = f2bf(a3 * inv);
    *reinterpret_cast<ushort4*>(&agg[(size_t)d * 256 + lane * 4]) = o;
}

// ---------------------------------------------------------------------------
// z = normalize(hp[:N_DST] + h2)   (bf16 in, fp32 out)
// ---------------------------------------------------------------------------
__global__ __launch_bounds__(256)
void skip_norm(const unsigned short* __restrict__ hp, const unsigned short* __restrict__ h2,
               float* __restrict__ z)
{
    __shared__ float sm[4];
    const int d = blockIdx.x, t = threadIdx.x;
    const float v = bf2f(hp[(size_t)d * 256 + t]) + bf2f(h2[(size_t)d * 256 + t]);
    float s = v * v;
#pragma unroll
    for (int off = 32; off > 0; off >>= 1) s += __shfl_down(s, off);
    if ((t & 63) == 0) sm[t >> 6] = s;
    __syncthreads();
    const float tot = sm[0] + sm[1] + sm[2] + sm[3];
    const float nrm = sqrtf(tot);
    const float inv = (nrm == 0.f) ? 1.f : 1.f / nrm;
    z[(size_t)d * 256 + t] = v * inv;
}

// ---------------------------------------------------------------------------
__global__ __launch_bounds__(256)
void score_kernel(const float* __restrict__ z, const float* __restrict__ bias,
                  const int* __restrict__ nids,
                  const int* __restrict__ ps, const int* __restrict__ pd,
                  const int* __restrict__ ns, const int* __restrict__ nd,
                  float* __restrict__ out)
{
    __shared__ float sm[8];
    const int p = blockIdx.x, t = threadIdx.x;
    const int a = ps[p], b = pd[p], c = ns[p], d2 = nd[p];
    float vp = z[(size_t)a * 256 + t] * z[(size_t)b * 256 + t];
    float vn = z[(size_t)c * 256 + t] * z[(size_t)d2 * 256 + t];
#pragma unroll
    for (int off = 32; off > 0; off >>= 1) {
        vp += __shfl_down(vp, off);
        vn += __shfl_down(vn, off);
    }
    if ((t & 63) == 0) { sm[t >> 6] = vp; sm[4 + (t >> 6)] = vn; }
    __syncthreads();
    if (t == 0) {
        const float pos = sm[0] + sm[1] + sm[2] + sm[3] + bias[nids[a]] + bias[nids[b]];
        const float neg = sm[4] + sm[5] + sm[6] + sm[7] + bias[nids[c]] + bias[nids[d2]];
        out[p] = fmaxf(neg - pos + 1.0f, 0.f);
    }
}

// ---------------------------------------------------------------------------
extern "C" void kernel_launch(void* const* d_in, const int* in_sizes, int n_in,
                              void* d_out, int out_size, void* d_ws, size_t ws_size,
                              hipStream_t stream)
{
    const float* feat = (const float*)d_in[0];
    const float* Wp   = (const float*)d_in[1];
    const float* bp   = (const float*)d_in[2];
    const float* Q1   = (const float*)d_in[3];
    const float* bq1  = (const float*)d_in[4];
    const float* W1   = (const float*)d_in[5];
    const float* bw1  = (const float*)d_in[6];
    const float* Q2   = (const float*)d_in[7];
    const float* bq2  = (const float*)d_in[8];
    const float* W2   = (const float*)d_in[9];
    const float* bw2  = (const float*)d_in[10];
    const float* w1   = (const float*)d_in[11];
    const float* w2   = (const float*)d_in[12];
    const float* bias = (const float*)d_in[13];
    const int* src1   = (const int*)d_in[14];
    const int* dst1   = (const int*)d_in[15];
    const int* src2   = (const int*)d_in[16];
    const int* dst2   = (const int*)d_in[17];
    const int* pos_src = (const int*)d_in[18];
    const int* pos_dst = (const int*)d_in[19];
    const int* neg_src = (const int*)d_in[20];
    const int* neg_dst = (const int*)d_in[21];
    const int* nids    = (const int*)d_in[22];

    // workspace layout (bf16 intermediates + bf16 weights + CSR)
    unsigned short* hp   = (unsigned short*)d_ws;              // [N_SRC,256]
    unsigned short* n1   = hp   + (size_t)N_SRC * 256;         // [N_SRC,256] (reused as n2)
    unsigned short* aggb = n1   + (size_t)N_SRC * 256;         // [N_MID,256] (reused as agg2)
    unsigned short* h1   = aggb + (size_t)N_MID * 256;         // [N_MID,256]
    unsigned short* h2   = h1   + (size_t)N_MID * 256;         // [N_DST,256]
    unsigned short* wb   = h2   + (size_t)N_DST * 256;         // 458752 bf16 weights
    float* zb            = (float*)(wb + 458752);              // [N_DST,256] fp32
    int* counts1 = (int*)(zb + (size_t)N_DST * 256);
    int* rs1     = counts1 + N_MID;
    int* cur1    = rs1 + N_MID + 1;
    int* ssrc1   = cur1 + N_MID;
    float* sw1   = (float*)(ssrc1 + E1);
    int* counts2 = (int*)(sw1 + E1);
    int* rs2     = counts2 + N_DST;
    int* cur2    = rs2 + N_DST + 1;
    int* ssrc2   = cur2 + N_DST;
    float* sw2   = (float*)(ssrc2 + E2);

    const unsigned short* Wpb = wb;
    const unsigned short* Q1b = wb + 65536;
    const unsigned short* W1b = wb + 131072;
    const unsigned short* Q2b = wb + 262144;
    const unsigned short* W2b = wb + 327680;

    hipMemsetAsync(counts1, 0, N_MID * sizeof(int), stream);
    hipMemsetAsync(counts2, 0, N_DST * sizeof(int), stream);

    const dim3 blk(256);
    conv_w<<<1792, blk, 0, stream>>>(Wp, Q1, W1, Q2, W2, wb);

    // hp = feat @ Wp^T + bp   (fp32 A staged to LDS, converted at frag-read)
    gemm_k<256, 1, 0><<<N_SRC / 64, 512, 0, stream>>>(
        feat, nullptr, Wpb, bp, hp, N_SRC);
    // n1 = relu(hp @ Q1^T + bq1)
    gemm_k<256, 0, 1><<<N_SRC / 64, 512, 0, stream>>>(
        hp, nullptr, Q1b, bq1, n1, N_SRC);

    // conv1 aggregation
    edge_count<<<1024, blk, 0, stream>>>(dst1, E1, counts1);
    scan_kernel<<<1, 1024, 0, stream>>>(counts1, N_MID, rs1, cur1);
    edge_fill<<<1024, blk, 0, stream>>>(dst1, src1, w1, E1, cur1, ssrc1, sw1);
    aggregate<<<N_MID / 4, blk, 0, stream>>>(n1, ssrc1, sw1, rs1, aggb);

    // h1 = relu( [agg1 | hp[:N_MID]] @ W1^T + bw1 )   (K=512 fused)
    gemm_k<512, 0, 1><<<N_MID / 64, 512, 0, stream>>>(
        aggb, hp, W1b, bw1, h1, N_MID);

    // n2 = relu(h1 @ Q2^T + bq2)   (into n1 buffer)
    gemm_k<256, 0, 1><<<N_MID / 64, 512, 0, stream>>>(
        h1, nullptr, Q2b, bq2, n1, N_MID);

    // conv2 aggregation
    edge_count<<<512, blk, 0, stream>>>(dst2, E2, counts2);
    scan_kernel<<<1, 1024, 0, stream>>>(counts2, N_DST, rs2, cur2);
    edge_fill<<<512, blk, 0, stream>>>(dst2, src2, w2, E2, cur2, ssrc2, sw2);
    aggregate<<<N_DST / 4, blk, 0, stream>>>(n1, ssrc2, sw2, rs2, aggb);

    // h2 = relu( [agg2 | h1[:N_DST]] @ W2^T + bw2 )   (K=512 fused)
    gemm_k<512, 0, 1><<<N_DST / 64, 512, 0, stream>>>(
        aggb, h1, W2b, bw2, h2, N_DST);

    // z = normalize(hp[:N_DST] + h2); scores
    skip_norm<<<N_DST, blk, 0, stream>>>(hp, h2, zb);
    score_kernel<<<N_PAIRS, blk, 0, stream>>>(zb, bias, nids,
                                              pos_src, pos_dst, neg_src, neg_dst,
                                              (float*)d_out);
}

// Round 6
// 291.892 us; speedup vs baseline: 1.9021x; 1.2615x over previous
//
#include <hip/hip_runtime.h>

#define HDIM 256
constexpr int N_SRC = 131072, N_MID = 32768, N_DST = 8192;
constexpr int E1 = 524288, E2 = 131072;
constexpr int N_PAIRS = 8192;

typedef __attribute__((ext_vector_type(8))) short bf16x8;
typedef __attribute__((ext_vector_type(4))) float f32x4;

__device__ __forceinline__ float bf2f(unsigned short u) {
    return __uint_as_float(((unsigned int)u) << 16);
}
__device__ __forceinline__ unsigned short f2bf(float f) {
    unsigned int x = __float_as_uint(f);
    x += 0x7fff + ((x >> 16) & 1);          // round-to-nearest-even
    return (unsigned short)(x >> 16);
}

// async global->LDS, 16B per lane; LDS dest = wave-uniform base + lane*16
__device__ __forceinline__ void gl16(const void* g, void* l)
{
    __builtin_amdgcn_global_load_lds(
        (const __attribute__((address_space(1))) unsigned int*)g,
        (__attribute__((address_space(3))) unsigned int*)l, 16, 0, 0);
}

// ---------------------------------------------------------------------------
// GEMM: C[M,256] = act( [A0|A1] @ W^T + bias ), bf16 out.
// Tile 64 rows x 256 cols per block (A read exactly once), BK=64,
// 512 threads = 8 waves, wave = 32x64 (wrow=w>>2, wc=w&3), acc 2x4 f32x4.
// Staging via global_load_lds(16B): LDS linear, 16B chunk index XOR-swizzled
// (kc ^= row&7) on the GLOBAL source; ds_read applies the same swizzle ->
// conflict-free frag reads (G21 both-sides pattern).
// ---------------------------------------------------------------------------
template<int KTOT, int FP32A, int ACT>
__global__ __launch_bounds__(512, 4)
void gemm_k(const void* __restrict__ A0v, const void* __restrict__ A1v,
            const unsigned short* __restrict__ Wb,
            const float* __restrict__ bias,
            unsigned short* __restrict__ C, int M)
{
    constexpr int KSTEPS = KTOT / 64;
    __shared__ unsigned short sW[256 * 64];                  // 32 KB
    __shared__ unsigned char  sA[FP32A ? 16384 : 8192];      // fp32: 16 KB
    unsigned char* sWb = (unsigned char*)sW;

    const int t = threadIdx.x;
    const int w = t >> 6, lane = t & 63;
    const int l15 = lane & 15;
    const int wrow = w >> 2, wc = w & 3;
    const int bm = blockIdx.x * 64;

    f32x4 acc[2][4];
#pragma unroll
    for (int m = 0; m < 2; ++m)
#pragma unroll
        for (int n = 0; n < 4; ++n) acc[m][n] = (f32x4){0.f, 0.f, 0.f, 0.f};

    for (int ks = 0; ks < KSTEPS; ++ks) {
        const int kw = ks * 64;
        // ---- stage W slice 256x64 (2048 slots, 4 iters) ----
#pragma unroll
        for (int it = 0; it < 4; ++it) {
            const int slot = it * 512 + w * 64 + lane;
            const int row = slot >> 3, kc = slot & 7;
            const int kcs = kc ^ (row & 7);
            gl16(&Wb[(size_t)row * KTOT + kw + kcs * 8],
                 sWb + (it * 512 + w * 64) * 16);
        }
        // ---- stage A slice 64x64 ----
        if constexpr (FP32A) {
            const float* A = (const float*)A0v;
#pragma unroll
            for (int it = 0; it < 2; ++it) {
                const int slot = it * 512 + w * 64 + lane;
                const int row = slot >> 4, kc = slot & 15;
                const int kcs = kc ^ (row & 7);
                gl16(&A[(size_t)(bm + row) * 256 + kw + kcs * 4],
                     sA + (it * 512 + w * 64) * 16);
            }
        } else {
            const unsigned short* A = (const unsigned short*)
                ((KTOT == 512 && ks >= 4) ? A1v : A0v);
            const int ka = (KTOT == 512) ? (ks & 3) * 64 : kw;
            const int slot = w * 64 + lane;
            const int row = slot >> 3, kc = slot & 7;
            const int kcs = kc ^ (row & 7);
            gl16(&A[(size_t)(bm + row) * 256 + ka + kcs * 8],
                 sA + (w * 64) * 16);
        }
        __syncthreads();   // drains vmcnt(0) then barrier

        // ---- compute: 2 k-slices x (2m x 4n) MFMA ----
#pragma unroll
        for (int kk = 0; kk < 2; ++kk) {
            const int kc = kk * 4 + (lane >> 4);
            bf16x8 afr[2], bfr[4];
#pragma unroll
            for (int m = 0; m < 2; ++m) {
                const int row = wrow * 32 + m * 16 + l15;
                if constexpr (FP32A) {
                    const int c0 = kk * 8 + (lane >> 4) * 2;
                    const float4 u0 = *(const float4*)(sA +
                        (((row << 4) | (c0 ^ (row & 7))) * 16));
                    const float4 u1 = *(const float4*)(sA +
                        (((row << 4) | ((c0 + 1) ^ (row & 7))) * 16));
                    bf16x8 r;
                    r[0] = (short)f2bf(u0.x); r[1] = (short)f2bf(u0.y);
                    r[2] = (short)f2bf(u0.z); r[3] = (short)f2bf(u0.w);
                    r[4] = (short)f2bf(u1.x); r[5] = (short)f2bf(u1.y);
                    r[6] = (short)f2bf(u1.z); r[7] = (short)f2bf(u1.w);
                    afr[m] = r;
                } else {
                    afr[m] = *(const bf16x8*)(sA +
                        (((row << 3) | (kc ^ (row & 7))) * 16));
                }
            }
#pragma unroll
            for (int n = 0; n < 4; ++n) {
                const int r = wc * 64 + n * 16 + l15;
                bfr[n] = *(const bf16x8*)(sWb +
                    (((r << 3) | (kc ^ (r & 7))) * 16));
            }
#pragma unroll
            for (int m = 0; m < 2; ++m)
#pragma unroll
                for (int n = 0; n < 4; ++n)
                    acc[m][n] = __builtin_amdgcn_mfma_f32_16x16x32_bf16(
                        afr[m], bfr[n], acc[m][n], 0, 0, 0);
        }
        __syncthreads();
    }

    // ---- epilogue: bias + act + bf16 store (burst; block covers full rows) --
    const int rb = (lane >> 4) * 4;
#pragma unroll
    for (int n = 0; n < 4; ++n) {
        const int col = wc * 64 + n * 16 + l15;
        const float bv = bias[col];
#pragma unroll
        for (int m = 0; m < 2; ++m) {
            const int row0 = bm + wrow * 32 + m * 16 + rb;
#pragma unroll
            for (int j = 0; j < 4; ++j) {
                float v = acc[m][n][j] + bv;
                if (ACT) v = fmaxf(v, 0.f);
                C[(size_t)(row0 + j) * 256 + col] = f2bf(v);
            }
        }
    }
}

// ---------------------------------------------------------------------------
// Convert the 5 weight matrices fp32 -> bf16
// ---------------------------------------------------------------------------
__global__ __launch_bounds__(256)
void conv_w(const float* __restrict__ Wp, const float* __restrict__ Q1,
            const float* __restrict__ W1, const float* __restrict__ Q2,
            const float* __restrict__ W2, unsigned short* __restrict__ out)
{
    const int i = blockIdx.x * 256 + threadIdx.x;
    const float* src; int off;
    if (i < 65536)       { src = Wp; off = i; }
    else if (i < 131072) { src = Q1; off = i - 65536; }
    else if (i < 262144) { src = W1; off = i - 131072; }
    else if (i < 327680) { src = Q2; off = i - 262144; }
    else                 { src = W2; off = i - 327680; }
    out[i] = f2bf(src[off]);
}

// ---------------------------------------------------------------------------
// CSR build: count -> scan -> fill
// ---------------------------------------------------------------------------
__global__ void edge_count(const int* __restrict__ dst, int E, int* __restrict__ counts)
{
    int i = blockIdx.x * blockDim.x + threadIdx.x;
    const int stride = gridDim.x * blockDim.x;
    for (; i < E; i += stride) atomicAdd(&counts[dst[i]], 1);
}

// Coalesced single-block scan: counts staged to LDS (padded rows, 2-way banks
// = free), per-thread chunk prefix in LDS, 1024-partial block scan, coalesced
// writeback of row_start+cursor. N = 1024*PER elements.
template<int PER>
__global__ __launch_bounds__(1024)
void scan_kernel(const int* __restrict__ counts,
                 int* __restrict__ row_start, int* __restrict__ cursor)
{
    constexpr int N = 1024 * PER;
    __shared__ int lds[1024][PER + 1];
    __shared__ int part[1024];
    const int t = threadIdx.x;
    for (int i = t; i < N; i += 1024) lds[i / PER][i % PER] = counts[i];
    __syncthreads();
    int s = 0;
#pragma unroll
    for (int j = 0; j < PER; ++j) s += lds[t][j];
    part[t] = s;
    __syncthreads();
    for (int off = 1; off < 1024; off <<= 1) {
        int v = (t >= off) ? part[t - off] : 0;
        __syncthreads();
        part[t] += v;
        __syncthreads();
    }
    int run = (t == 0) ? 0 : part[t - 1];   // exclusive prefix of chunks
#pragma unroll
    for (int j = 0; j < PER; ++j) {
        const int c = lds[t][j];
        lds[t][j] = run;
        run += c;
    }
    __syncthreads();
    for (int i = t; i < N; i += 1024) {
        const int v = lds[i / PER][i % PER];
        row_start[i] = v;
        cursor[i] = v;
    }
    if (t == 1023) row_start[N] = run;      // grand total
}

__global__ void edge_fill(const int* __restrict__ dst, const int* __restrict__ src,
                          const float* __restrict__ w, int E,
                          int* __restrict__ cursor,
                          int* __restrict__ ssrc, float* __restrict__ sw)
{
    int i = blockIdx.x * blockDim.x + threadIdx.x;
    const int stride = gridDim.x * blockDim.x;
    for (; i < E; i += stride) {
        const int p = atomicAdd(&cursor[dst[i]], 1);
        ssrc[p] = src[i];
        sw[p]   = w[i];
    }
}

// ---------------------------------------------------------------------------
// Weighted aggregate with 4x memory-level parallelism (one wave per dst row).
// ---------------------------------------------------------------------------
__global__ __launch_bounds__(256)
void aggregate(const unsigned short* __restrict__ nsrc,
               const int* __restrict__ ssrc, const float* __restrict__ sw,
               const int* __restrict__ rs, unsigned short* __restrict__ agg)
{
    const int d = blockIdx.x * 4 + (threadIdx.x >> 6);
    const int lane = threadIdx.x & 63;
    const int p0 = rs[d], p1 = rs[d + 1];
    float a0 = 0.f, a1 = 0.f, a2 = 0.f, a3 = 0.f, wacc = 0.f;

    for (int base = p0; base < p1; base += 64) {
        const int cnt = min(64, p1 - base);
        int   mySrc = 0;
        float myW   = 0.f;
        if (lane < cnt) { mySrc = ssrc[base + lane]; myW = sw[base + lane]; }
        wacc += myW;
        int j = 0;
        for (; j + 4 <= cnt; j += 4) {
            const int   s0 = __shfl(mySrc, j + 0), s1 = __shfl(mySrc, j + 1);
            const int   s2 = __shfl(mySrc, j + 2), s3 = __shfl(mySrc, j + 3);
            const float w0 = __shfl(myW, j + 0),   w1 = __shfl(myW, j + 1);
            const float w2 = __shfl(myW, j + 2),   w3 = __shfl(myW, j + 3);
            const ushort4 r0 = *reinterpret_cast<const ushort4*>(&nsrc[(size_t)s0 * 256 + lane * 4]);
            const ushort4 r1 = *reinterpret_cast<const ushort4*>(&nsrc[(size_t)s1 * 256 + lane * 4]);
            const ushort4 r2 = *reinterpret_cast<const ushort4*>(&nsrc[(size_t)s2 * 256 + lane * 4]);
            const ushort4 r3 = *reinterpret_cast<const ushort4*>(&nsrc[(size_t)s3 * 256 + lane * 4]);
            a0 += bf2f(r0.x) * w0; a1 += bf2f(r0.y) * w0; a2 += bf2f(r0.z) * w0; a3 += bf2f(r0.w) * w0;
            a0 += bf2f(r1.x) * w1; a1 += bf2f(r1.y) * w1; a2 += bf2f(r1.z) * w1; a3 += bf2f(r1.w) * w1;
            a0 += bf2f(r2.x) * w2; a1 += bf2f(r2.y) * w2; a2 += bf2f(r2.z) * w2; a3 += bf2f(r2.w) * w2;
            a0 += bf2f(r3.x) * w3; a1 += bf2f(r3.y) * w3; a2 += bf2f(r3.z) * w3; a3 += bf2f(r3.w) * w3;
        }
        for (; j < cnt; ++j) {
            const int   s = __shfl(mySrc, j);
            const float wj = __shfl(myW, j);
            const ushort4 r = *reinterpret_cast<const ushort4*>(&nsrc[(size_t)s * 256 + lane * 4]);
            a0 += bf2f(r.x) * wj; a1 += bf2f(r.y) * wj; a2 += bf2f(r.z) * wj; a3 += bf2f(r.w) * wj;
        }
    }
    float ws = wacc;
#pragma unroll
    for (int off = 32; off > 0; off >>= 1) ws += __shfl_xor(ws, off);
    const float inv = 1.f / fmaxf(ws, 1.f);
    ushort4 o;
    o.x = f2bf(a0 * inv); o.y = f2bf(a1 * inv);
    o.z = f2bf(a2 * inv); o.w = f2bf(a3 * inv);
    *reinterpret_cast<ushort4*>(&agg[(size_t)d * 256 + lane * 4]) = o;
}

// ---------------------------------------------------------------------------
// z = normalize(hp[:N_DST] + h2)   (bf16 in, fp32 out)
// ---------------------------------------------------------------------------
__global__ __launch_bounds__(256)
void skip_norm(const unsigned short* __restrict__ hp, const unsigned short* __restrict__ h2,
               float* __restrict__ z)
{
    __shared__ float sm[4];
    const int d = blockIdx.x, t = threadIdx.x;
    const float v = bf2f(hp[(size_t)d * 256 + t]) + bf2f(h2[(size_t)d * 256 + t]);
    float s = v * v;
#pragma unroll
    for (int off = 32; off > 0; off >>= 1) s += __shfl_down(s, off);
    if ((t & 63) == 0) sm[t >> 6] = s;
    __syncthreads();
    const float tot = sm[0] + sm[1] + sm[2] + sm[3];
    const float nrm = sqrtf(tot);
    const float inv = (nrm == 0.f) ? 1.f : 1.f / nrm;
    z[(size_t)d * 256 + t] = v * inv;
}

// ---------------------------------------------------------------------------
__global__ __launch_bounds__(256)
void score_kernel(const float* __restrict__ z, const float* __restrict__ bias,
                  const int* __restrict__ nids,
                  const int* __restrict__ ps, const int* __restrict__ pd,
                  const int* __restrict__ ns, const int* __restrict__ nd,
                  float* __restrict__ out)
{
    __shared__ float sm[8];
    const int p = blockIdx.x, t = threadIdx.x;
    const int a = ps[p], b = pd[p], c = ns[p], d2 = nd[p];
    float vp = z[(size_t)a * 256 + t] * z[(size_t)b * 256 + t];
    float vn = z[(size_t)c * 256 + t] * z[(size_t)d2 * 256 + t];
#pragma unroll
    for (int off = 32; off > 0; off >>= 1) {
        vp += __shfl_down(vp, off);
        vn += __shfl_down(vn, off);
    }
    if ((t & 63) == 0) { sm[t >> 6] = vp; sm[4 + (t >> 6)] = vn; }
    __syncthreads();
    if (t == 0) {
        const float pos = sm[0] + sm[1] + sm[2] + sm[3] + bias[nids[a]] + bias[nids[b]];
        const float neg = sm[4] + sm[5] + sm[6] + sm[7] + bias[nids[c]] + bias[nids[d2]];
        out[p] = fmaxf(neg - pos + 1.0f, 0.f);
    }
}

// ---------------------------------------------------------------------------
extern "C" void kernel_launch(void* const* d_in, const int* in_sizes, int n_in,
                              void* d_out, int out_size, void* d_ws, size_t ws_size,
                              hipStream_t stream)
{
    const float* feat = (const float*)d_in[0];
    const float* Wp   = (const float*)d_in[1];
    const float* bp   = (const float*)d_in[2];
    const float* Q1   = (const float*)d_in[3];
    const float* bq1  = (const float*)d_in[4];
    const float* W1   = (const float*)d_in[5];
    const float* bw1  = (const float*)d_in[6];
    const float* Q2   = (const float*)d_in[7];
    const float* bq2  = (const float*)d_in[8];
    const float* W2   = (const float*)d_in[9];
    const float* bw2  = (const float*)d_in[10];
    const float* w1   = (const float*)d_in[11];
    const float* w2   = (const float*)d_in[12];
    const float* bias = (const float*)d_in[13];
    const int* src1   = (const int*)d_in[14];
    const int* dst1   = (const int*)d_in[15];
    const int* src2   = (const int*)d_in[16];
    const int* dst2   = (const int*)d_in[17];
    const int* pos_src = (const int*)d_in[18];
    const int* pos_dst = (const int*)d_in[19];
    const int* neg_src = (const int*)d_in[20];
    const int* neg_dst = (const int*)d_in[21];
    const int* nids    = (const int*)d_in[22];

    // workspace layout (bf16 intermediates + bf16 weights + CSR)
    unsigned short* hp   = (unsigned short*)d_ws;              // [N_SRC,256]
    unsigned short* n1   = hp   + (size_t)N_SRC * 256;         // [N_SRC,256] (reused as n2)
    unsigned short* aggb = n1   + (size_t)N_SRC * 256;         // [N_MID,256] (reused as agg2)
    unsigned short* h1   = aggb + (size_t)N_MID * 256;         // [N_MID,256]
    unsigned short* h2   = h1   + (size_t)N_MID * 256;         // [N_DST,256]
    unsigned short* wb   = h2   + (size_t)N_DST * 256;         // 458752 bf16 weights
    float* zb            = (float*)(wb + 458752);              // [N_DST,256] fp32
    int* counts1 = (int*)(zb + (size_t)N_DST * 256);
    int* rs1     = counts1 + N_MID;
    int* cur1    = rs1 + N_MID + 1;
    int* ssrc1   = cur1 + N_MID;
    float* sw1   = (float*)(ssrc1 + E1);
    int* counts2 = (int*)(sw1 + E1);
    int* rs2     = counts2 + N_DST;
    int* cur2    = rs2 + N_DST + 1;
    int* ssrc2   = cur2 + N_DST;
    float* sw2   = (float*)(ssrc2 + E2);

    const unsigned short* Wpb = wb;
    const unsigned short* Q1b = wb + 65536;
    const unsigned short* W1b = wb + 131072;
    const unsigned short* Q2b = wb + 262144;
    const unsigned short* W2b = wb + 327680;

    hipMemsetAsync(counts1, 0, N_MID * sizeof(int), stream);
    hipMemsetAsync(counts2, 0, N_DST * sizeof(int), stream);

    const dim3 blk(256);
    conv_w<<<1792, blk, 0, stream>>>(Wp, Q1, W1, Q2, W2, wb);

    // hp = feat @ Wp^T + bp   (fp32 A staged to LDS, converted at frag-read)
    gemm_k<256, 1, 0><<<N_SRC / 64, 512, 0, stream>>>(
        feat, nullptr, Wpb, bp, hp, N_SRC);
    // n1 = relu(hp @ Q1^T + bq1)
    gemm_k<256, 0, 1><<<N_SRC / 64, 512, 0, stream>>>(
        hp, nullptr, Q1b, bq1, n1, N_SRC);

    // conv1 aggregation
    edge_count<<<1024, blk, 0, stream>>>(dst1, E1, counts1);
    scan_kernel<32><<<1, 1024, 0, stream>>>(counts1, rs1, cur1);
    edge_fill<<<1024, blk, 0, stream>>>(dst1, src1, w1, E1, cur1, ssrc1, sw1);
    aggregate<<<N_MID / 4, blk, 0, stream>>>(n1, ssrc1, sw1, rs1, aggb);

    // h1 = relu( [agg1 | hp[:N_MID]] @ W1^T + bw1 )   (K=512 fused)
    gemm_k<512, 0, 1><<<N_MID / 64, 512, 0, stream>>>(
        aggb, hp, W1b, bw1, h1, N_MID);

    // n2 = relu(h1 @ Q2^T + bq2)   (into n1 buffer)
    gemm_k<256, 0, 1><<<N_MID / 64, 512, 0, stream>>>(
        h1, nullptr, Q2b, bq2, n1, N_MID);

    // conv2 aggregation
    edge_count<<<512, blk, 0, stream>>>(dst2, E2, counts2);
    scan_kernel<8><<<1, 1024, 0, stream>>>(counts2, rs2, cur2);
    edge_fill<<<512, blk, 0, stream>>>(dst2, src2, w2, E2, cur2, ssrc2, sw2);
    aggregate<<<N_DST / 4, blk, 0, stream>>>(n1, ssrc2, sw2, rs2, aggb);

    // h2 = relu( [agg2 | h1[:N_DST]] @ W2^T + bw2 )   (K=512 fused)
    gemm_k<512, 0, 1><<<N_DST / 64, 512, 0, stream>>>(
        aggb, h1, W2b, bw2, h2, N_DST);

    // z = normalize(hp[:N_DST] + h2); scores
    skip_norm<<<N_DST, blk, 0, stream>>>(hp, h2, zb);
    score_kernel<<<N_PAIRS, blk, 0, stream>>>(zb, bias, nids,
                                              pos_src, pos_dst, neg_src, neg_dst,
                                              (float*)d_out);
}

// Round 7
// 258.865 us; speedup vs baseline: 2.1447x; 1.1276x over previous
//
#include <hip/hip_runtime.h>

#define HDIM 256
constexpr int N_SRC = 131072, N_MID = 32768, N_DST = 8192;
constexpr int E1 = 524288, E2 = 131072;
constexpr int N_PAIRS = 8192;

typedef __attribute__((ext_vector_type(8))) short bf16x8;
typedef __attribute__((ext_vector_type(4))) float f32x4;

__device__ __forceinline__ float bf2f(unsigned short u) {
    return __uint_as_float(((unsigned int)u) << 16);
}
__device__ __forceinline__ unsigned short f2bf(float f) {
    unsigned int x = __float_as_uint(f);
    x += 0x7fff + ((x >> 16) & 1);          // round-to-nearest-even
    return (unsigned short)(x >> 16);
}

// async global->LDS, 16B per lane; LDS dest = wave-uniform base + lane*16
__device__ __forceinline__ void gl16(const void* g, void* l)
{
    __builtin_amdgcn_global_load_lds(
        (const __attribute__((address_space(1))) unsigned int*)g,
        (__attribute__((address_space(3))) unsigned int*)l, 16, 0, 0);
}

// ---------------------------------------------------------------------------
// gemm_k (unfused, used for h2): C[M,256] = act([A0|A1] @ W^T + bias), bf16.
// Tile 64x256/block, BK=64, 8 waves, wave=32x64. global_load_lds staging with
// XOR-swizzled source + swizzled ds_read (proven round 5/6).
// ---------------------------------------------------------------------------
template<int KTOT, int FP32A, int ACT>
__global__ __launch_bounds__(512, 4)
void gemm_k(const void* __restrict__ A0v, const void* __restrict__ A1v,
            const unsigned short* __restrict__ Wb,
            const float* __restrict__ bias,
            unsigned short* __restrict__ C, int M)
{
    constexpr int KSTEPS = KTOT / 64;
    __shared__ unsigned short sW[256 * 64];                  // 32 KB
    __shared__ unsigned char  sA[FP32A ? 16384 : 8192];
    unsigned char* sWb = (unsigned char*)sW;

    const int t = threadIdx.x;
    const int w = t >> 6, lane = t & 63;
    const int l15 = lane & 15;
    const int wrow = w >> 2, wc = w & 3;
    const int bm = blockIdx.x * 64;

    f32x4 acc[2][4];
#pragma unroll
    for (int m = 0; m < 2; ++m)
#pragma unroll
        for (int n = 0; n < 4; ++n) acc[m][n] = (f32x4){0.f, 0.f, 0.f, 0.f};

    for (int ks = 0; ks < KSTEPS; ++ks) {
        const int kw = ks * 64;
#pragma unroll
        for (int it = 0; it < 4; ++it) {
            const int slot = it * 512 + w * 64 + lane;
            const int row = slot >> 3, kc = slot & 7;
            const int kcs = kc ^ (row & 7);
            gl16(&Wb[(size_t)row * KTOT + kw + kcs * 8],
                 sWb + (it * 512 + w * 64) * 16);
        }
        if constexpr (FP32A) {
            const float* A = (const float*)A0v;
#pragma unroll
            for (int it = 0; it < 2; ++it) {
                const int slot = it * 512 + w * 64 + lane;
                const int row = slot >> 4, kc = slot & 15;
                const int kcs = kc ^ (row & 7);
                gl16(&A[(size_t)(bm + row) * 256 + kw + kcs * 4],
                     sA + (it * 512 + w * 64) * 16);
            }
        } else {
            const unsigned short* A = (const unsigned short*)
                ((KTOT == 512 && ks >= 4) ? A1v : A0v);
            const int ka = (KTOT == 512) ? (ks & 3) * 64 : kw;
            const int slot = w * 64 + lane;
            const int row = slot >> 3, kc = slot & 7;
            const int kcs = kc ^ (row & 7);
            gl16(&A[(size_t)(bm + row) * 256 + ka + kcs * 8],
                 sA + (w * 64) * 16);
        }
        __syncthreads();

#pragma unroll
        for (int kk = 0; kk < 2; ++kk) {
            const int kc = kk * 4 + (lane >> 4);
            bf16x8 afr[2], bfr[4];
#pragma unroll
            for (int m = 0; m < 2; ++m) {
                const int row = wrow * 32 + m * 16 + l15;
                if constexpr (FP32A) {
                    const int c0 = kk * 8 + (lane >> 4) * 2;
                    const float4 u0 = *(const float4*)(sA +
                        (((row << 4) | (c0 ^ (row & 7))) * 16));
                    const float4 u1 = *(const float4*)(sA +
                        (((row << 4) | ((c0 + 1) ^ (row & 7))) * 16));
                    bf16x8 r;
                    r[0] = (short)f2bf(u0.x); r[1] = (short)f2bf(u0.y);
                    r[2] = (short)f2bf(u0.z); r[3] = (short)f2bf(u0.w);
                    r[4] = (short)f2bf(u1.x); r[5] = (short)f2bf(u1.y);
                    r[6] = (short)f2bf(u1.z); r[7] = (short)f2bf(u1.w);
                    afr[m] = r;
                } else {
                    afr[m] = *(const bf16x8*)(sA +
                        (((row << 3) | (kc ^ (row & 7))) * 16));
                }
            }
#pragma unroll
            for (int n = 0; n < 4; ++n) {
                const int r = wc * 64 + n * 16 + l15;
                bfr[n] = *(const bf16x8*)(sWb +
                    (((r << 3) | (kc ^ (r & 7))) * 16));
            }
#pragma unroll
            for (int m = 0; m < 2; ++m)
#pragma unroll
                for (int n = 0; n < 4; ++n)
                    acc[m][n] = __builtin_amdgcn_mfma_f32_16x16x32_bf16(
                        afr[m], bfr[n], acc[m][n], 0, 0, 0);
        }
        __syncthreads();
    }

    const int rb = (lane >> 4) * 4;
#pragma unroll
    for (int n = 0; n < 4; ++n) {
        const int col = wc * 64 + n * 16 + l15;
        const float bv = bias[col];
#pragma unroll
        for (int m = 0; m < 2; ++m) {
            const int row0 = bm + wrow * 32 + m * 16 + rb;
#pragma unroll
            for (int j = 0; j < 4; ++j) {
                float v = acc[m][n][j] + bv;
                if (ACT) v = fmaxf(v, 0.f);
                C[(size_t)(row0 + j) * 256 + col] = f2bf(v);
            }
        }
    }
}

// ---------------------------------------------------------------------------
// FUSED double GEMM:
//   T  = act1( [A0|A1] @ W^T + bias1 )        (KTOT1 = 256 or 512)
//   C2 = act2( T @ Q^T + bias2 )              (K = 256)
// T's 64x256 block tile is kept in LDS (XOR-swizzled 16B chunks) and written
// to global C1 only for rows < M1lim (M1lim multiple of 64).
// Eliminates a full M-row GEMM dispatch + T re-read from HBM.
// ---------------------------------------------------------------------------
template<int KTOT1, int FP32A, int ACT1, int ACT2>
__global__ __launch_bounds__(512, 4)
void gemm_fused(const void* __restrict__ A0v, const void* __restrict__ A1v,
                const unsigned short* __restrict__ Wb,   // [256][KTOT1]
                const float* __restrict__ bias1,
                unsigned short* __restrict__ C1, int M1lim,
                const unsigned short* __restrict__ Qb,   // [256][256]
                const float* __restrict__ bias2,
                unsigned short* __restrict__ C2, int M)
{
    constexpr int KSTEPS = KTOT1 / 64;
    __shared__ unsigned short sW[256 * 64];                  // 32 KB W/Q slices
    __shared__ unsigned char  sA[FP32A ? 16384 : 8192];
    __shared__ unsigned short sHP[64 * 256];                 // 32 KB T tile
    unsigned char* sWb  = (unsigned char*)sW;
    unsigned char* sHPb = (unsigned char*)sHP;

    const int t = threadIdx.x;
    const int w = t >> 6, lane = t & 63;
    const int l15 = lane & 15;
    const int wrow = w >> 2, wc = w & 3;
    const int bm = blockIdx.x * 64;
    const int rb = (lane >> 4) * 4;

    f32x4 acc[2][4];
#pragma unroll
    for (int m = 0; m < 2; ++m)
#pragma unroll
        for (int n = 0; n < 4; ++n) acc[m][n] = (f32x4){0.f, 0.f, 0.f, 0.f};

    // ================= phase 1: first GEMM =================
    for (int ks = 0; ks < KSTEPS; ++ks) {
        const int kw = ks * 64;
#pragma unroll
        for (int it = 0; it < 4; ++it) {
            const int slot = it * 512 + w * 64 + lane;
            const int row = slot >> 3, kc = slot & 7;
            const int kcs = kc ^ (row & 7);
            gl16(&Wb[(size_t)row * KTOT1 + kw + kcs * 8],
                 sWb + (it * 512 + w * 64) * 16);
        }
        if constexpr (FP32A) {
            const float* A = (const float*)A0v;
#pragma unroll
            for (int it = 0; it < 2; ++it) {
                const int slot = it * 512 + w * 64 + lane;
                const int row = slot >> 4, kc = slot & 15;
                const int kcs = kc ^ (row & 7);
                gl16(&A[(size_t)(bm + row) * 256 + kw + kcs * 4],
                     sA + (it * 512 + w * 64) * 16);
            }
        } else {
            const unsigned short* A = (const unsigned short*)
                ((KTOT1 == 512 && ks >= 4) ? A1v : A0v);
            const int ka = (KTOT1 == 512) ? (ks & 3) * 64 : kw;
            const int slot = w * 64 + lane;
            const int row = slot >> 3, kc = slot & 7;
            const int kcs = kc ^ (row & 7);
            gl16(&A[(size_t)(bm + row) * 256 + ka + kcs * 8],
                 sA + (w * 64) * 16);
        }
        __syncthreads();

#pragma unroll
        for (int kk = 0; kk < 2; ++kk) {
            const int kc = kk * 4 + (lane >> 4);
            bf16x8 afr[2], bfr[4];
#pragma unroll
            for (int m = 0; m < 2; ++m) {
                const int row = wrow * 32 + m * 16 + l15;
                if constexpr (FP32A) {
                    const int c0 = kk * 8 + (lane >> 4) * 2;
                    const float4 u0 = *(const float4*)(sA +
                        (((row << 4) | (c0 ^ (row & 7))) * 16));
                    const float4 u1 = *(const float4*)(sA +
                        (((row << 4) | ((c0 + 1) ^ (row & 7))) * 16));
                    bf16x8 r;
                    r[0] = (short)f2bf(u0.x); r[1] = (short)f2bf(u0.y);
                    r[2] = (short)f2bf(u0.z); r[3] = (short)f2bf(u0.w);
                    r[4] = (short)f2bf(u1.x); r[5] = (short)f2bf(u1.y);
                    r[6] = (short)f2bf(u1.z); r[7] = (short)f2bf(u1.w);
                    afr[m] = r;
                } else {
                    afr[m] = *(const bf16x8*)(sA +
                        (((row << 3) | (kc ^ (row & 7))) * 16));
                }
            }
#pragma unroll
            for (int n = 0; n < 4; ++n) {
                const int r = wc * 64 + n * 16 + l15;
                bfr[n] = *(const bf16x8*)(sWb +
                    (((r << 3) | (kc ^ (r & 7))) * 16));
            }
#pragma unroll
            for (int m = 0; m < 2; ++m)
#pragma unroll
                for (int n = 0; n < 4; ++n)
                    acc[m][n] = __builtin_amdgcn_mfma_f32_16x16x32_bf16(
                        afr[m], bfr[n], acc[m][n], 0, 0, 0);
        }
        __syncthreads();
    }

    // ====== phase 2: epilogue1 -> sHP (swizzled) + partial global C1 ======
    const bool wr1 = (bm < M1lim);
#pragma unroll
    for (int n = 0; n < 4; ++n) {
        const int col = wc * 64 + n * 16 + l15;
        const float bv = bias1[col];
        const int c = col >> 3, cl = col & 7;
#pragma unroll
        for (int m = 0; m < 2; ++m) {
            const int row0 = wrow * 32 + m * 16 + rb;
#pragma unroll
            for (int j = 0; j < 4; ++j) {
                float v = acc[m][n][j] + bv;
                if (ACT1) v = fmaxf(v, 0.f);
                const unsigned short b = f2bf(v);
                const int r = row0 + j;
                sHP[r * 256 + (c ^ (r & 7)) * 8 + cl] = b;
                if (wr1) C1[(size_t)(bm + r) * 256 + col] = b;
            }
        }
    }
    __syncthreads();

    // ================= phase 3: second GEMM (T @ Q^T) =================
#pragma unroll
    for (int m = 0; m < 2; ++m)
#pragma unroll
        for (int n = 0; n < 4; ++n) acc[m][n] = (f32x4){0.f, 0.f, 0.f, 0.f};

    for (int ks2 = 0; ks2 < 4; ++ks2) {
#pragma unroll
        for (int it = 0; it < 4; ++it) {
            const int slot = it * 512 + w * 64 + lane;
            const int row = slot >> 3, kc = slot & 7;
            const int kcs = kc ^ (row & 7);
            gl16(&Qb[(size_t)row * 256 + ks2 * 64 + kcs * 8],
                 sWb + (it * 512 + w * 64) * 16);
        }
        __syncthreads();
#pragma unroll
        for (int kk = 0; kk < 2; ++kk) {
            const int kc = kk * 4 + (lane >> 4);
            bf16x8 afr[2], bfr[4];
#pragma unroll
            for (int m = 0; m < 2; ++m) {
                const int r = wrow * 32 + m * 16 + l15;
                const int cch = ks2 * 8 + kc;
                afr[m] = *(const bf16x8*)(sHPb + r * 512 + (cch ^ (r & 7)) * 16);
            }
#pragma unroll
            for (int n = 0; n < 4; ++n) {
                const int r = wc * 64 + n * 16 + l15;
                bfr[n] = *(const bf16x8*)(sWb +
                    (((r << 3) | (kc ^ (r & 7))) * 16));
            }
#pragma unroll
            for (int m = 0; m < 2; ++m)
#pragma unroll
                for (int n = 0; n < 4; ++n)
                    acc[m][n] = __builtin_amdgcn_mfma_f32_16x16x32_bf16(
                        afr[m], bfr[n], acc[m][n], 0, 0, 0);
        }
        __syncthreads();
    }

    // ================= phase 4: epilogue2 -> C2 (full) =================
#pragma unroll
    for (int n = 0; n < 4; ++n) {
        const int col = wc * 64 + n * 16 + l15;
        const float bv = bias2[col];
#pragma unroll
        for (int m = 0; m < 2; ++m) {
            const int row0 = bm + wrow * 32 + m * 16 + rb;
#pragma unroll
            for (int j = 0; j < 4; ++j) {
                float v = acc[m][n][j] + bv;
                if (ACT2) v = fmaxf(v, 0.f);
                C2[(size_t)(row0 + j) * 256 + col] = f2bf(v);
            }
        }
    }
}

// ---------------------------------------------------------------------------
// Convert the 5 weight matrices fp32 -> bf16
// ---------------------------------------------------------------------------
__global__ __launch_bounds__(256)
void conv_w(const float* __restrict__ Wp, const float* __restrict__ Q1,
            const float* __restrict__ W1, const float* __restrict__ Q2,
            const float* __restrict__ W2, unsigned short* __restrict__ out)
{
    const int i = blockIdx.x * 256 + threadIdx.x;
    const float* src; int off;
    if (i < 65536)       { src = Wp; off = i; }
    else if (i < 131072) { src = Q1; off = i - 65536; }
    else if (i < 262144) { src = W1; off = i - 131072; }
    else if (i < 327680) { src = Q2; off = i - 262144; }
    else                 { src = W2; off = i - 327680; }
    out[i] = f2bf(src[off]);
}

// ---------------------------------------------------------------------------
// CSR build (both graphs fused): count -> scan -> fill
// ---------------------------------------------------------------------------
__global__ void edge_count2(const int* __restrict__ dst1, const int* __restrict__ dst2,
                            int* __restrict__ counts1, int* __restrict__ counts2)
{
    const int i = blockIdx.x * blockDim.x + threadIdx.x;
    if (i < E1) atomicAdd(&counts1[dst1[i]], 1);
    else        atomicAdd(&counts2[dst2[i - E1]], 1);
}

// Coalesced single-block scan (LDS-staged). N = 1024*PER.
template<int PER>
__global__ __launch_bounds__(1024)
void scan_kernel(const int* __restrict__ counts,
                 int* __restrict__ row_start, int* __restrict__ cursor)
{
    constexpr int N = 1024 * PER;
    __shared__ int lds[1024][PER + 1];
    __shared__ int part[1024];
    const int t = threadIdx.x;
    for (int i = t; i < N; i += 1024) lds[i / PER][i % PER] = counts[i];
    __syncthreads();
    int s = 0;
#pragma unroll
    for (int j = 0; j < PER; ++j) s += lds[t][j];
    part[t] = s;
    __syncthreads();
    for (int off = 1; off < 1024; off <<= 1) {
        int v = (t >= off) ? part[t - off] : 0;
        __syncthreads();
        part[t] += v;
        __syncthreads();
    }
    int run = (t == 0) ? 0 : part[t - 1];
#pragma unroll
    for (int j = 0; j < PER; ++j) {
        const int c = lds[t][j];
        lds[t][j] = run;
        run += c;
    }
    __syncthreads();
    for (int i = t; i < N; i += 1024) {
        const int v = lds[i / PER][i % PER];
        row_start[i] = v;
        cursor[i] = v;
    }
    if (t == 1023) row_start[N] = run;
}

__global__ void edge_fill2(const int* __restrict__ dst1, const int* __restrict__ src1,
                           const float* __restrict__ w1,
                           const int* __restrict__ dst2, const int* __restrict__ src2,
                           const float* __restrict__ w2,
                           int* __restrict__ cur1, int* __restrict__ cur2,
                           int* __restrict__ ssrc1, float* __restrict__ sw1,
                           int* __restrict__ ssrc2, float* __restrict__ sw2)
{
    const int i = blockIdx.x * blockDim.x + threadIdx.x;
    if (i < E1) {
        const int p = atomicAdd(&cur1[dst1[i]], 1);
        ssrc1[p] = src1[i];
        sw1[p]   = w1[i];
    } else {
        const int j = i - E1;
        const int p = atomicAdd(&cur2[dst2[j]], 1);
        ssrc2[p] = src2[j];
        sw2[p]   = w2[j];
    }
}

// ---------------------------------------------------------------------------
// Weighted aggregate with 4x memory-level parallelism (one wave per dst row).
// ---------------------------------------------------------------------------
__global__ __launch_bounds__(256)
void aggregate(const unsigned short* __restrict__ nsrc,
               const int* __restrict__ ssrc, const float* __restrict__ sw,
               const int* __restrict__ rs, unsigned short* __restrict__ agg)
{
    const int d = blockIdx.x * 4 + (threadIdx.x >> 6);
    const int lane = threadIdx.x & 63;
    const int p0 = rs[d], p1 = rs[d + 1];
    float a0 = 0.f, a1 = 0.f, a2 = 0.f, a3 = 0.f, wacc = 0.f;

    for (int base = p0; base < p1; base += 64) {
        const int cnt = min(64, p1 - base);
        int   mySrc = 0;
        float myW   = 0.f;
        if (lane < cnt) { mySrc = ssrc[base + lane]; myW = sw[base + lane]; }
        wacc += myW;
        int j = 0;
        for (; j + 4 <= cnt; j += 4) {
            const int   s0 = __shfl(mySrc, j + 0), s1 = __shfl(mySrc, j + 1);
            const int   s2 = __shfl(mySrc, j + 2), s3 = __shfl(mySrc, j + 3);
            const float w0 = __shfl(myW, j + 0),   w1 = __shfl(myW, j + 1);
            const float w2 = __shfl(myW, j + 2),   w3 = __shfl(myW, j + 3);
            const ushort4 r0 = *reinterpret_cast<const ushort4*>(&nsrc[(size_t)s0 * 256 + lane * 4]);
            const ushort4 r1 = *reinterpret_cast<const ushort4*>(&nsrc[(size_t)s1 * 256 + lane * 4]);
            const ushort4 r2 = *reinterpret_cast<const ushort4*>(&nsrc[(size_t)s2 * 256 + lane * 4]);
            const ushort4 r3 = *reinterpret_cast<const ushort4*>(&nsrc[(size_t)s3 * 256 + lane * 4]);
            a0 += bf2f(r0.x) * w0; a1 += bf2f(r0.y) * w0; a2 += bf2f(r0.z) * w0; a3 += bf2f(r0.w) * w0;
            a0 += bf2f(r1.x) * w1; a1 += bf2f(r1.y) * w1; a2 += bf2f(r1.z) * w1; a3 += bf2f(r1.w) * w1;
            a0 += bf2f(r2.x) * w2; a1 += bf2f(r2.y) * w2; a2 += bf2f(r2.z) * w2; a3 += bf2f(r2.w) * w2;
            a0 += bf2f(r3.x) * w3; a1 += bf2f(r3.y) * w3; a2 += bf2f(r3.z) * w3; a3 += bf2f(r3.w) * w3;
        }
        for (; j < cnt; ++j) {
            const int   s = __shfl(mySrc, j);
            const float wj = __shfl(myW, j);
            const ushort4 r = *reinterpret_cast<const ushort4*>(&nsrc[(size_t)s * 256 + lane * 4]);
            a0 += bf2f(r.x) * wj; a1 += bf2f(r.y) * wj; a2 += bf2f(r.z) * wj; a3 += bf2f(r.w) * wj;
        }
    }
    float ws = wacc;
#pragma unroll
    for (int off = 32; off > 0; off >>= 1) ws += __shfl_xor(ws, off);
    const float inv = 1.f / fmaxf(ws, 1.f);
    ushort4 o;
    o.x = f2bf(a0 * inv); o.y = f2bf(a1 * inv);
    o.z = f2bf(a2 * inv); o.w = f2bf(a3 * inv);
    *reinterpret_cast<ushort4*>(&agg[(size_t)d * 256 + lane * 4]) = o;
}

// ---------------------------------------------------------------------------
// z = normalize(hp[:N_DST] + h2)   (bf16 in, fp32 out)
// ---------------------------------------------------------------------------
__global__ __launch_bounds__(256)
void skip_norm(const unsigned short* __restrict__ hp, const unsigned short* __restrict__ h2,
               float* __restrict__ z)
{
    __shared__ float sm[4];
    const int d = blockIdx.x, t = threadIdx.x;
    const float v = bf2f(hp[(size_t)d * 256 + t]) + bf2f(h2[(size_t)d * 256 + t]);
    float s = v * v;
#pragma unroll
    for (int off = 32; off > 0; off >>= 1) s += __shfl_down(s, off);
    if ((t & 63) == 0) sm[t >> 6] = s;
    __syncthreads();
    const float tot = sm[0] + sm[1] + sm[2] + sm[3];
    const float nrm = sqrtf(tot);
    const float inv = (nrm == 0.f) ? 1.f : 1.f / nrm;
    z[(size_t)d * 256 + t] = v * inv;
}

// ---------------------------------------------------------------------------
__global__ __launch_bounds__(256)
void score_kernel(const float* __restrict__ z, const float* __restrict__ bias,
                  const int* __restrict__ nids,
                  const int* __restrict__ ps, const int* __restrict__ pd,
                  const int* __restrict__ ns, const int* __restrict__ nd,
                  float* __restrict__ out)
{
    __shared__ float sm[8];
    const int p = blockIdx.x, t = threadIdx.x;
    const int a = ps[p], b = pd[p], c = ns[p], d2 = nd[p];
    float vp = z[(size_t)a * 256 + t] * z[(size_t)b * 256 + t];
    float vn = z[(size_t)c * 256 + t] * z[(size_t)d2 * 256 + t];
#pragma unroll
    for (int off = 32; off > 0; off >>= 1) {
        vp += __shfl_down(vp, off);
        vn += __shfl_down(vn, off);
    }
    if ((t & 63) == 0) { sm[t >> 6] = vp; sm[4 + (t >> 6)] = vn; }
    __syncthreads();
    if (t == 0) {
        const float pos = sm[0] + sm[1] + sm[2] + sm[3] + bias[nids[a]] + bias[nids[b]];
        const float neg = sm[4] + sm[5] + sm[6] + sm[7] + bias[nids[c]] + bias[nids[d2]];
        out[p] = fmaxf(neg - pos + 1.0f, 0.f);
    }
}

// ---------------------------------------------------------------------------
extern "C" void kernel_launch(void* const* d_in, const int* in_sizes, int n_in,
                              void* d_out, int out_size, void* d_ws, size_t ws_size,
                              hipStream_t stream)
{
    const float* feat = (const float*)d_in[0];
    const float* Wp   = (const float*)d_in[1];
    const float* bp   = (const float*)d_in[2];
    const float* Q1   = (const float*)d_in[3];
    const float* bq1  = (const float*)d_in[4];
    const float* W1   = (const float*)d_in[5];
    const float* bw1  = (const float*)d_in[6];
    const float* Q2   = (const float*)d_in[7];
    const float* bq2  = (const float*)d_in[8];
    const float* W2   = (const float*)d_in[9];
    const float* bw2  = (const float*)d_in[10];
    const float* w1   = (const float*)d_in[11];
    const float* w2   = (const float*)d_in[12];
    const float* bias = (const float*)d_in[13];
    const int* src1   = (const int*)d_in[14];
    const int* dst1   = (const int*)d_in[15];
    const int* src2   = (const int*)d_in[16];
    const int* dst2   = (const int*)d_in[17];
    const int* pos_src = (const int*)d_in[18];
    const int* pos_dst = (const int*)d_in[19];
    const int* neg_src = (const int*)d_in[20];
    const int* neg_dst = (const int*)d_in[21];
    const int* nids    = (const int*)d_in[22];

    // workspace layout
    unsigned short* hp   = (unsigned short*)d_ws;              // [N_SRC,256] (only :N_MID written)
    unsigned short* n1   = hp   + (size_t)N_SRC * 256;         // [N_SRC,256] (reused as n2)
    unsigned short* aggb = n1   + (size_t)N_SRC * 256;         // [N_MID,256] (reused as agg2)
    unsigned short* h1   = aggb + (size_t)N_MID * 256;         // [N_MID,256] (only :N_DST written)
    unsigned short* h2   = h1   + (size_t)N_MID * 256;         // [N_DST,256]
    unsigned short* wb   = h2   + (size_t)N_DST * 256;         // 458752 bf16 weights
    float* zb            = (float*)(wb + 458752);              // [N_DST,256] fp32
    int* counts1 = (int*)(zb + (size_t)N_DST * 256);
    int* counts2 = counts1 + N_MID;                            // adjacent -> one memset
    int* rs1     = counts2 + N_DST;
    int* cur1    = rs1 + N_MID + 1;
    int* ssrc1   = cur1 + N_MID;
    float* sw1   = (float*)(ssrc1 + E1);
    int* rs2     = (int*)(sw1 + E1);
    int* cur2    = rs2 + N_DST + 1;
    int* ssrc2   = cur2 + N_DST;
    float* sw2   = (float*)(ssrc2 + E2);

    const unsigned short* Wpb = wb;
    const unsigned short* Q1b = wb + 65536;
    const unsigned short* W1b = wb + 131072;
    const unsigned short* Q2b = wb + 262144;
    const unsigned short* W2b = wb + 327680;

    hipMemsetAsync(counts1, 0, (N_MID + N_DST) * sizeof(int), stream);

    const dim3 blk(256);
    conv_w<<<1792, blk, 0, stream>>>(Wp, Q1, W1, Q2, W2, wb);

    // hp = feat @ Wp^T + bp (rows<N_MID to global); n1 = relu(hp @ Q1^T + bq1)
    gemm_fused<256, 1, 0, 1><<<N_SRC / 64, 512, 0, stream>>>(
        feat, nullptr, Wpb, bp, hp, N_MID, Q1b, bq1, n1, N_SRC);

    // CSR build (both graphs)
    edge_count2<<<(E1 + E2) / 256, blk, 0, stream>>>(dst1, dst2, counts1, counts2);
    scan_kernel<32><<<1, 1024, 0, stream>>>(counts1, rs1, cur1);
    scan_kernel<8><<<1, 1024, 0, stream>>>(counts2, rs2, cur2);
    edge_fill2<<<(E1 + E2) / 256, blk, 0, stream>>>(dst1, src1, w1, dst2, src2, w2,
                                                    cur1, cur2, ssrc1, sw1, ssrc2, sw2);

    // conv1 aggregation
    aggregate<<<N_MID / 4, blk, 0, stream>>>(n1, ssrc1, sw1, rs1, aggb);

    // h1 = relu([agg1|hp]@W1^T + bw1) (rows<N_DST); n2 = relu(h1 @ Q2^T + bq2)
    gemm_fused<512, 0, 1, 1><<<N_MID / 64, 512, 0, stream>>>(
        aggb, hp, W1b, bw1, h1, N_DST, Q2b, bq2, n1, N_MID);

    // conv2 aggregation
    aggregate<<<N_DST / 4, blk, 0, stream>>>(n1, ssrc2, sw2, rs2, aggb);

    // h2 = relu( [agg2 | h1[:N_DST]] @ W2^T + bw2 )
    gemm_k<512, 0, 1><<<N_DST / 64, 512, 0, stream>>>(
        aggb, h1, W2b, bw2, h2, N_DST);

    // z = normalize(hp[:N_DST] + h2); scores
    skip_norm<<<N_DST, blk, 0, stream>>>(hp, h2, zb);
    score_kernel<<<N_PAIRS, blk, 0, stream>>>(zb, bias, nids,
                                              pos_src, pos_dst, neg_src, neg_dst,
                                              (float*)d_out);
}